// Round 8
// baseline (188.814 us; speedup 1.0000x reference)
//
#include <hip/hip_runtime.h>

#define HW     3136      // 56*56
#define WIDTH  56
#define C      256
#define CR     64
#define NT     64
#define TT     8
#define PW     64        // padded row width (bf16 y)
#define PH     58        // padded rows
#define YPLANE (PH*PW)   // 3712 shorts per (nt,ch) plane
#define YBYTES ((size_t)NT * CR * YPLANE * 2)   // 30,408,704 (16B-aligned)

#define BN_INV 0.9999950000374997f   // 1/sqrt(1+1e-5)

typedef __attribute__((ext_vector_type(8))) short short8;
typedef __attribute__((ext_vector_type(8))) unsigned short ushort8;
typedef __attribute__((ext_vector_type(4))) float f32x4;
typedef __attribute__((ext_vector_type(2))) float f32x2;

static __device__ __forceinline__ float relu(float v) { return fmaxf(v, 0.0f); }
static __device__ __forceinline__ float bf2f(unsigned short u) {
    return __builtin_bit_cast(float, (unsigned)u << 16);
}
static __device__ __forceinline__ unsigned short f2bf(float f) {
    unsigned u = __builtin_bit_cast(unsigned, f);
    unsigned r = (u + 0x7FFFu + ((u >> 16) & 1u)) >> 16;   // RNE
    return (unsigned short)r;
}
static __device__ __forceinline__ unsigned pack2(float a, float b) {
    return (unsigned)f2bf(a) | ((unsigned)f2bf(b) << 16);
}

// zero the halo cells of all 64 planes of frame nt (rows 0,57; col 0; cols 57..63)
static __device__ __forceinline__ void halo_zero(int nt, int tid,
                                                 unsigned short* __restrict__ y) {
    const int ch = tid >> 2, part = tid & 3;
    unsigned short* pl = y + ((size_t)nt * CR + ch) * YPLANE;
    if (part == 0) {
        ushort8 z = (ushort8)0;
#pragma unroll
        for (int j = 0; j < 8; ++j) *(ushort8*)(pl + j * 8) = z;          // row 0
    } else if (part == 1) {
        ushort8 z = (ushort8)0;
        unsigned short* q = pl + 57 * PW;                                  // row 57
#pragma unroll
        for (int j = 0; j < 8; ++j) *(ushort8*)(q + j * 8) = z;
    } else if (part == 2) {
        for (int r = 1; r <= 28; ++r) {
            unsigned short* q = pl + r * PW + 57;
#pragma unroll
            for (int j = 0; j < 8; ++j) q[j] = 0;
        }
    } else {
        for (int r = 29; r <= 56; ++r) {
            unsigned short* q = pl + r * PW + 57;
#pragma unroll
            for (int j = 0; j < 8; ++j) q[j] = 0;
        }
        pl[PW] = 0;                                                        // row 1 col 0
    }
}

// k1: blocks 0..783 (XCD-swizzled): y = relu(bn21(conv21(x))) via MFMA -> bf16 padded.
//     blocks 784..847: halo-zero (overlapped).
__global__ __launch_bounds__(256, 2) void k1_mfma(const float* __restrict__ x,
                                                  const float* __restrict__ w21,
                                                  const float* __restrict__ g,
                                                  const float* __restrict__ bb,
                                                  unsigned short* __restrict__ y) {
    const int blk = blockIdx.x;
    const int tid = threadIdx.x;
    if (blk >= 784) { halo_zero(blk - 784, tid, y); return; }
    // bijective XCD swizzle (784 = 8*98): each XCD gets 98 consecutive logical blocks
    const int bs = (blk & 7) * 98 + (blk >> 3);

    __shared__ unsigned short Alds[64][264];     // 64 o x (256 c + 8 pad) = 33 KB
    __shared__ unsigned short Blds[4][64][40];   // per-wave 64 px x (32 c + 8 pad) = 20 KB

    const int lane = tid & 63;
    const int wv   = tid >> 6;
    const int gq   = bs / 49;
    const int s    = bs - gq * 49;
    const int p0   = s * 64;
    const int nt   = __builtin_amdgcn_readfirstlane(gq * 4 + wv);

    {   // stage A: convert fp32 weights in-block (w is L2/L3-hot across blocks)
        const int o  = tid >> 2;
        const int cb = (tid & 3) * 64;
        const float* wp = w21 + o * C + cb;
        unsigned short* ap = &Alds[o][cb];
#pragma unroll
        for (int j = 0; j < 8; ++j) {
            f32x4 lo = *(const f32x4*)(wp + j * 8);
            f32x4 hi = *(const f32x4*)(wp + j * 8 + 4);
            union { unsigned d[4]; short8 v; } pk;
            pk.d[0] = pack2(lo.x, lo.y); pk.d[1] = pack2(lo.z, lo.w);
            pk.d[2] = pack2(hi.x, hi.y); pk.d[3] = pack2(hi.z, hi.w);
            *(short8*)(ap + j * 8) = pk.v;
        }
    }
    __syncthreads();   // the only barrier

    const float* xw = x + (size_t)nt * (C * HW) + p0 + lane;
    unsigned short (*Bw)[40] = Blds[wv];

    f32x4 acc[4][4];
#pragma unroll
    for (int nb = 0; nb < 4; ++nb)
#pragma unroll
        for (int mb = 0; mb < 4; ++mb) acc[nb][mb] = (f32x4)0.0f;

    const int frow = lane & 15;
    const int fk8  = (lane >> 4) * 8;

    float buf[2][32];
#pragma unroll
    for (int j = 0; j < 32; ++j) buf[0][j] = xw[(size_t)j * HW];

#pragma unroll
    for (int ks = 0; ks < 8; ++ks) {
        const int cur = ks & 1;
        if (ks < 7) {
            const float* xn = xw + (size_t)((ks + 1) * 32) * HW;
#pragma unroll
            for (int j = 0; j < 32; ++j) buf[cur ^ 1][j] = xn[(size_t)j * HW];
        }
#pragma unroll
        for (int q = 0; q < 4; ++q) {
            union { unsigned d[4]; short8 v; } pk;
#pragma unroll
            for (int jj = 0; jj < 4; ++jj)
                pk.d[jj] = pack2(buf[cur][q * 8 + 2 * jj], buf[cur][q * 8 + 2 * jj + 1]);
            *(short8*)&Bw[lane][q * 8] = pk.v;
        }
        short8 bfrag[4], afrag[4];
#pragma unroll
        for (int nb = 0; nb < 4; ++nb)
            bfrag[nb] = *(const short8*)&Bw[nb * 16 + frow][fk8];
#pragma unroll
        for (int mb = 0; mb < 4; ++mb)
            afrag[mb] = *(const short8*)&Alds[mb * 16 + frow][ks * 32 + fk8];
#pragma unroll
        for (int nb = 0; nb < 4; ++nb)
#pragma unroll
            for (int mb = 0; mb < 4; ++mb)
                acc[nb][mb] = __builtin_amdgcn_mfma_f32_16x16x32_bf16(
                    afrag[mb], bfrag[nb], acc[nb][mb], 0, 0, 0);
    }

    // epilogue: D col = lane&15 (pixel), row = (lane>>4)*4 + r (output o); bf16 store
    unsigned short* ybase = y + (size_t)nt * CR * YPLANE;
    const int rbase = (lane >> 4) * 4;
#pragma unroll
    for (int nb = 0; nb < 4; ++nb) {
        const int p = p0 + nb * 16 + frow;
        const int r = p / WIDTH;
        const int c = p - r * WIDTH;
        const int pidx = (r + 1) * PW + (c + 1);
#pragma unroll
        for (int mb = 0; mb < 4; ++mb)
#pragma unroll
            for (int rr = 0; rr < 4; ++rr) {
                int o = mb * 16 + rbase + rr;
                float v = relu(fmaf(acc[nb][mb][rr], g[o] * BN_INV, bb[o]));
                ybase[(size_t)o * YPLANE + pidx] = f2bf(v);
            }
    }
}

// k2: cv[nt,k,p] = relu(bn22( (1/CR) * sum_ch y1*y2(shifted) )).  (round-5 proven)
// Thread = (task, ch-quarter); task = (nt, row, 8-col group). No masks (halo).
__global__ __launch_bounds__(256) void k2_corr(const unsigned short* __restrict__ y,
                                               const float* __restrict__ g,
                                               const float* __restrict__ bb,
                                               float* __restrict__ cv) {
    const int bs = (blockIdx.x & 7) * 49 + (blockIdx.x >> 3);   // 392 = 8*49
    int gt   = bs * 256 + threadIdx.x;           // 0..100351
    int h    = gt & 3;                           // ch quarter
    int task = gt >> 2;                          // 0..25087
    int nt   = task / 392;                       // 392 = 56 rows * 7 cgroups
    int rm   = task - nt * 392;
    int r    = rm / 7;
    int cg   = rm - r * 7;
    int c0   = cg * 8;
    int nt2  = ((nt & (TT - 1)) < TT - 1) ? nt + 1 : nt;

    const unsigned short* y1 = y + ((size_t)nt * CR + h * 16) * YPLANE
                                 + (size_t)(r + 1) * PW + c0;
    const unsigned short* y2 = y + ((size_t)nt2 * CR + h * 16) * YPLANE
                                 + (size_t)r * PW + c0;

    float acc[9][8];
#pragma unroll
    for (int k = 0; k < 9; ++k)
#pragma unroll
        for (int px = 0; px < 8; ++px) acc[k][px] = 0.0f;

#pragma unroll 2
    for (int ch = 0; ch < 16; ++ch) {
        const unsigned short* p1 = y1 + (size_t)ch * YPLANE;
        ushort8 a8 = *(const ushort8*)p1;
        unsigned at = *(const unsigned*)(p1 + 8);
        float a[8];
#pragma unroll
        for (int j = 0; j < 7; ++j) a[j] = bf2f(a8[j + 1]);
        a[7] = bf2f((unsigned short)(at & 0xffffu));

        const unsigned short* p2 = y2 + (size_t)ch * YPLANE;
#pragma unroll
        for (int dy = 0; dy < 3; ++dy) {
            const unsigned short* pr = p2 + dy * PW;
            ushort8 b8 = *(const ushort8*)pr;
            unsigned bt = *(const unsigned*)(pr + 8);
            float w[10];
#pragma unroll
            for (int j = 0; j < 8; ++j) w[j] = bf2f(b8[j]);
            w[8] = bf2f((unsigned short)(bt & 0xffffu));
            w[9] = bf2f((unsigned short)(bt >> 16));
#pragma unroll
            for (int dx = 0; dx < 3; ++dx) {
                int k = dy * 3 + dx;
#pragma unroll
                for (int px = 0; px < 8; ++px)
                    acc[k][px] = fmaf(a[px], w[px + dx], acc[k][px]);
            }
        }
    }

    // reduce across the 4 ch-quarter lanes (xor 1, xor 2)
#pragma unroll
    for (int k = 0; k < 9; ++k)
#pragma unroll
        for (int px = 0; px < 8; ++px) {
            float v = acc[k][px];
            v += __shfl_xor(v, 1);
            v += __shfl_xor(v, 2);
            acc[k][px] = v;
        }

    if (h == 0) {
        float* cp = cv + (size_t)nt * 9 * HW + r * WIDTH + c0;
        const float rcr = 1.0f / CR;
#pragma unroll
        for (int k = 0; k < 9; ++k) {
            float sc = g[k] * BN_INV, bv = bb[k];
            f32x4 lo, hi;
            lo.x = relu(fmaf(acc[k][0] * rcr, sc, bv));
            lo.y = relu(fmaf(acc[k][1] * rcr, sc, bv));
            lo.z = relu(fmaf(acc[k][2] * rcr, sc, bv));
            lo.w = relu(fmaf(acc[k][3] * rcr, sc, bv));
            hi.x = relu(fmaf(acc[k][4] * rcr, sc, bv));
            hi.y = relu(fmaf(acc[k][5] * rcr, sc, bv));
            hi.z = relu(fmaf(acc[k][6] * rcr, sc, bv));
            hi.w = relu(fmaf(acc[k][7] * rcr, sc, bv));
            *(f32x4*)(cp + (size_t)k * HW)     = lo;
            *(f32x4*)(cp + (size_t)k * HW + 4) = hi;
        }
    }
}

// k3: out[nt,o,p] = relu( bn23( sum_k w2[o,k]*cv[nt,k,p] ) + x[nt,o,p] ).
// (round-5 proven) 2 pixels/thread (float2), 392 blocks x 256 thr; uniform o-loop.
__global__ __launch_bounds__(256) void k3_conv22(const float* __restrict__ cv,
                                                 const float* __restrict__ w2,
                                                 const float* __restrict__ g,
                                                 const float* __restrict__ bb,
                                                 const float* __restrict__ x,
                                                 float* __restrict__ out) {
    const int bs = (blockIdx.x & 7) * 49 + (blockIdx.x >> 3);   // 392 = 8*49
    int gt = bs * 256 + threadIdx.x;           // 0..100351
    int nt = gt / 1568;                        // 1568 = 3136/2
    int p2 = (gt - nt * 1568) * 2;

    const float* cp = cv + (size_t)nt * 9 * HW + p2;
    float cvx[9], cvy[9];
#pragma unroll
    for (int k = 0; k < 9; ++k) {
        f32x2 v = *(const f32x2*)(cp + (size_t)k * HW);
        cvx[k] = v.x; cvy[k] = v.y;
    }

    const float* xp = x   + (size_t)nt * (C * HW) + p2;
    float*       op = out + (size_t)nt * (C * HW) + p2;

#pragma unroll 8
    for (int o = 0; o < C; ++o) {
        const float* wr = w2 + o * 9;
        f32x2 xr = *(const f32x2*)(xp + (size_t)o * HW);
        float sx = 0.0f, sy = 0.0f;
#pragma unroll
        for (int k = 0; k < 9; ++k) {
            float wv = wr[k];
            sx = fmaf(wv, cvx[k], sx);
            sy = fmaf(wv, cvy[k], sy);
        }
        float sc = g[o] * BN_INV, bv = bb[o];
        f32x2 rv;
        rv.x = relu(fmaf(sx, sc, bv) + xr.x);
        rv.y = relu(fmaf(sy, sc, bv) + xr.y);
        *(f32x2*)(op + (size_t)o * HW) = rv;
    }
}

extern "C" void kernel_launch(void* const* d_in, const int* in_sizes, int n_in,
                              void* d_out, int out_size, void* d_ws, size_t ws_size,
                              hipStream_t stream) {
    const float* x   = (const float*)d_in[0];
    const float* w21 = (const float*)d_in[1];
    const float* g21 = (const float*)d_in[2];
    const float* b21 = (const float*)d_in[3];
    const float* g22 = (const float*)d_in[4];
    const float* b22 = (const float*)d_in[5];
    const float* w22 = (const float*)d_in[6];
    const float* g23 = (const float*)d_in[7];
    const float* b23 = (const float*)d_in[8];
    float* out = (float*)d_out;

    // ws layout: y bf16 padded (30.4MB) then cv fp32 (7.2MB)
    unsigned short* yb  = (unsigned short*)d_ws;
    float*          cvb = (float*)((char*)d_ws + YBYTES);

    k1_mfma  <<<848, 256, 0, stream>>>(x, w21, g21, b21, yb);
    k2_corr  <<<392, 256, 0, stream>>>(yb, g22, b22, cvb);
    k3_conv22<<<392, 256, 0, stream>>>(cvb, w22, g23, b23, x, out);
}